// Round 1
// baseline (451.388 us; speedup 1.0000x reference)
//
#include <hip/hip_runtime.h>
#include <hip/hip_bf16.h>

typedef short bf16x8 __attribute__((ext_vector_type(8)));
typedef float f32x4  __attribute__((ext_vector_type(4)));

#define H_NODE 64
#define H_EDGE 128
#define IN_DIM 256
#define WAVES  16
#define BLOCK  1024
#define GRID   256
#define LN_EPS 1e-5f

// Static LDS layout (byte offsets), 160 KiB total (full CU LDS, 1 block/CU):
//   [0,      65536): W1^T bf16: addr = col*512 + ((k*2) ^ ((col&7)<<4)),  col in [0,128), k in [0,256)
//   [65536,  98304): W2^T bf16: addr = 65536 + col*256 + ((k*2) ^ ((col&7)<<4)), k in [0,128)
//   [98304, 163840): per-wave transpose tile (16 rows x 128 bf16, 4KB x 16 waves),
//                    used twice per tile: h (post-GEMM1) then w (post-LN).
//
// Pipeline (1-tile-deep software pipeline, T14 async-stage):
//   top:        issue NEXT tile's node gathers (raw f32x4) + b1 reload   [covered by GEMM1]
//   post-h:     issue NEXT tile's edge gathers + tile+2 indices,
//               fold node prefetch -> A1[0..3] (dead after GEMM1)        [covered by GEMM2]
//   post-GEMM2: reload LN constants, fold edge prefetch -> A1n[4..7]
//   end:        A1[4..7] <- A1n (cur edge frags needed for residual until store)
// Streaming data (edgef, out, ei) uses non-temporal loads/stores so the ~1GB
// streams don't thrash L1/L2; node table (12.8MB) keeps cache residency.

static __device__ __forceinline__ short f2bf(float x) {
    __hip_bfloat16 h = __float2bfloat16(x);   // RNE
    return *reinterpret_cast<short*>(&h);
}

static __device__ __forceinline__ float bf2f(short s) {
    union { unsigned int u; float f; } v;
    v.u = ((unsigned int)(unsigned short)s) << 16;
    return v.f;
}

static __device__ __forceinline__ int tswz(int r, int g) {
    return r * 256 + ((g ^ ((r >> 2) << 1)) << 4);
}

static __device__ __forceinline__ bf16x8 cvt8(f32x4 lo, f32x4 hi) {
    bf16x8 f;
    f[0] = f2bf(lo[0]); f[1] = f2bf(lo[1]); f[2] = f2bf(lo[2]); f[3] = f2bf(lo[3]);
    f[4] = f2bf(hi[0]); f[5] = f2bf(hi[1]); f[6] = f2bf(hi[2]); f[7] = f2bf(hi[3]);
    return f;
}

extern "C" __global__ void __launch_bounds__(BLOCK, 4)
edge_update(const float* __restrict__ node,
            const float* __restrict__ edgef,
            const int* __restrict__ ei,          // int32 on device
            const float* __restrict__ W1, const float* __restrict__ b1,
            const float* __restrict__ W2, const float* __restrict__ b2,
            const float* __restrict__ gamma, const float* __restrict__ beta,
            float* __restrict__ out, int E)
{
    __shared__ char lds[163840];
    const int tid = threadIdx.x;

    // ---- stage W1^T (bf16, swizzled) ----
    #pragma unroll 4
    for (int i = 0; i < 32; ++i) {
        int e = tid + i * 1024;             // e < 32768; W1 is [k][n], k<256, n<128
        int k = e >> 7, n = e & 127;
        float v = W1[e];
        int addr = n * 512 + ((k * 2) ^ ((n & 7) << 4));
        *(short*)(lds + addr) = f2bf(v);
    }
    // ---- stage W2^T ----
    #pragma unroll 4
    for (int i = 0; i < 16; ++i) {
        int e = tid + i * 1024;             // e < 16384; W2 is [k][n], k<128, n<128
        int k = e >> 7, n = e & 127;
        float v = W2[e];
        int addr = 65536 + n * 256 + ((k * 2) ^ ((n & 7) << 4));
        *(short*)(lds + addr) = f2bf(v);
    }
    __syncthreads();

    const int wid   = tid >> 6;
    const int lane  = tid & 63;
    const int lrow  = lane & 15;   // A-frag row / C col / B col
    const int lk8   = lane >> 4;   // k-subchunk 0..3
    const int hbase = 98304 + wid * 4096;

    const int ntiles  = (E + 15) >> 4;
    const int wstride = GRID * WAVES;

    int tile = blockIdx.x * WAVES + wid;
    if (tile >= ntiles) return;

    // ---- prologue: gather this tile's A1 (blocking, once) ----
    int rowg = tile * 16 + lrow; if (rowg >= E) rowg = E - 1;
    int sidx = __builtin_nontemporal_load(ei + rowg);
    int didx = __builtin_nontemporal_load(ei + E + rowg);
    bf16x8 A1[8];
    {
        const float* srcp = node + (size_t)sidx * H_NODE + lk8 * 8;
        const float* dstp = node + (size_t)didx * H_NODE + lk8 * 8;
        const float* egp  = edgef + (size_t)rowg * H_EDGE + lk8 * 8;
        #pragma unroll
        for (int t = 0; t < 4; ++t) {
            const float* p = (t < 2) ? (srcp + t * 32) : (dstp + (t - 2) * 32);
            A1[t] = cvt8(*(const f32x4*)p, *(const f32x4*)(p + 4));
        }
        #pragma unroll
        for (int t = 0; t < 4; ++t) {
            f32x4 lo = __builtin_nontemporal_load((const f32x4*)(egp + t * 32));
            f32x4 hi = __builtin_nontemporal_load((const f32x4*)(egp + t * 32 + 4));
            A1[4 + t] = cvt8(lo, hi);
        }
    }
    // indices for tile+1 (clamped; redundant loads past the end are harmless)
    int next  = tile + wstride;
    int nrowg = next * 16 + lrow; if (nrowg >= E) nrowg = E - 1;
    int nsidx = __builtin_nontemporal_load(ei + nrowg);
    int ndidx = __builtin_nontemporal_load(ei + E + nrowg);

    while (tile < ntiles) {
        // ---- issue NEXT tile's node gathers (raw; convert after GEMM1) ----
        const float* nsrcp = node + (size_t)nsidx * H_NODE + lk8 * 8;
        const float* ndstp = node + (size_t)ndidx * H_NODE + lk8 * 8;
        f32x4 Fn0 = *(const f32x4*)(nsrcp);
        f32x4 Fn1 = *(const f32x4*)(nsrcp + 4);
        f32x4 Fn2 = *(const f32x4*)(nsrcp + 32);
        f32x4 Fn3 = *(const f32x4*)(nsrcp + 36);
        f32x4 Fn4 = *(const f32x4*)(ndstp);
        f32x4 Fn5 = *(const f32x4*)(ndstp + 4);
        f32x4 Fn6 = *(const f32x4*)(ndstp + 32);
        f32x4 Fn7 = *(const f32x4*)(ndstp + 36);
        // b1 reload (L1-hot broadcast lines), used at h-phase; covered by GEMM1
        float b1v[8];
        #pragma unroll
        for (int n = 0; n < 8; ++n) b1v[n] = b1[n * 16 + lrow];

        // ---- GEMM1: [16x256] @ [256x128] ----
        f32x4 acc[8];
        #pragma unroll
        for (int n = 0; n < 8; ++n) acc[n] = (f32x4){0.f, 0.f, 0.f, 0.f};
        #pragma unroll
        for (int n = 0; n < 8; ++n) {
            const int col = n * 16 + lrow;
            const int cb  = col * 512;
            const int sw  = (col & 7) << 4;
            #pragma unroll
            for (int t = 0; t < 8; ++t) {
                int kb = t * 64 + lk8 * 16;
                bf16x8 bfrag = *(const bf16x8*)(lds + cb + (kb ^ sw));
                acc[n] = __builtin_amdgcn_mfma_f32_16x16x32_bf16(A1[t], bfrag, acc[n], 0, 0, 0);
            }
        }

        // ---- bias + relu -> h (bf16) to per-wave LDS (conflict-free swizzle) ----
        #pragma unroll
        for (int n = 0; n < 8; ++n) {
            const int g = n * 2 + (lrow >> 3);
            const int cl = (lrow & 7) * 2;
            #pragma unroll
            for (int i = 0; i < 4; ++i) {
                float u = fmaxf(acc[n][i] + b1v[n], 0.f);
                int row = lk8 * 4 + i;
                *(short*)(lds + hbase + tswz(row, g) + cl) = f2bf(u);
            }
        }
        // same-wave cross-lane LDS visibility: drain ds_writes before reads
        asm volatile("s_waitcnt lgkmcnt(0)" ::: "memory");

        // ---- issue NEXT tile's edge gathers + tile+2 indices ----
        const float* negp = edgef + (size_t)nrowg * H_EDGE + lk8 * 8;
        f32x4 Fe0 = __builtin_nontemporal_load((const f32x4*)(negp));
        f32x4 Fe1 = __builtin_nontemporal_load((const f32x4*)(negp + 4));
        f32x4 Fe2 = __builtin_nontemporal_load((const f32x4*)(negp + 32));
        f32x4 Fe3 = __builtin_nontemporal_load((const f32x4*)(negp + 36));
        f32x4 Fe4 = __builtin_nontemporal_load((const f32x4*)(negp + 64));
        f32x4 Fe5 = __builtin_nontemporal_load((const f32x4*)(negp + 68));
        f32x4 Fe6 = __builtin_nontemporal_load((const f32x4*)(negp + 96));
        f32x4 Fe7 = __builtin_nontemporal_load((const f32x4*)(negp + 100));
        int t2 = next + wstride;
        int t2rowg = t2 * 16 + lrow; if (t2rowg >= E) t2rowg = E - 1;
        int t2s = __builtin_nontemporal_load(ei + t2rowg);
        int t2d = __builtin_nontemporal_load(ei + E + t2rowg);

        // ---- fold node prefetch into A1[0..3] (dead after GEMM1) ----
        A1[0] = cvt8(Fn0, Fn1);
        A1[1] = cvt8(Fn2, Fn3);
        A1[2] = cvt8(Fn4, Fn5);
        A1[3] = cvt8(Fn6, Fn7);

        // ---- GEMM2: [16x128] @ [128x128] ----
        bf16x8 A2[4];
        #pragma unroll
        for (int t = 0; t < 4; ++t)
            A2[t] = *(const bf16x8*)(lds + hbase + tswz(lrow, t * 4 + lk8));

        f32x4 acc2[8];
        #pragma unroll
        for (int n = 0; n < 8; ++n) acc2[n] = (f32x4){0.f, 0.f, 0.f, 0.f};
        #pragma unroll
        for (int n = 0; n < 8; ++n) {
            const int col = n * 16 + lrow;
            const int cb  = 65536 + col * 256;
            const int sw  = (col & 7) << 4;
            #pragma unroll
            for (int t = 0; t < 4; ++t) {
                int kb = t * 64 + lk8 * 16;
                bf16x8 bfrag = *(const bf16x8*)(lds + cb + (kb ^ sw));
                acc2[n] = __builtin_amdgcn_mfma_f32_16x16x32_bf16(A2[t], bfrag, acc2[n], 0, 0, 0);
            }
        }

        // ---- LN constants reload (L1-hot) + fold edge prefetch into A1n ----
        // (A1[4..7] still holds CURRENT tile's edge frags for the residual)
        float b2v[8], gv[8], btv[8];
        #pragma unroll
        for (int n = 0; n < 8; ++n) {
            int c = n * 16 + lrow;
            b2v[n] = b2[c]; gv[n] = gamma[c]; btv[n] = beta[c];
        }
        bf16x8 A1n4 = cvt8(Fe0, Fe1);
        bf16x8 A1n5 = cvt8(Fe2, Fe3);
        bf16x8 A1n6 = cvt8(Fe4, Fe5);
        bf16x8 A1n7 = cvt8(Fe6, Fe7);

        // ---- bias2 + LayerNorm (C-layout) -> w (bf16) back through LDS ----
        #pragma unroll
        for (int i = 0; i < 4; ++i) {
            float s = 0.f, sq = 0.f;
            #pragma unroll
            for (int n = 0; n < 8; ++n) {
                float u = acc2[n][i] + b2v[n];
                s  += u;
                sq += u * u;
            }
            #pragma unroll
            for (int m = 1; m < 16; m <<= 1) {
                s  += __shfl_xor(s,  m, 64);
                sq += __shfl_xor(sq, m, 64);
            }
            float mu  = s * (1.f / 128.f);
            float var = sq * (1.f / 128.f) - mu * mu;
            float rs  = rsqrtf(var + LN_EPS);
            int row = lk8 * 4 + i;
            const int cl = (lrow & 7) * 2;
            #pragma unroll
            for (int n = 0; n < 8; ++n) {
                float u = acc2[n][i] + b2v[n];    // recompute: saves 8 live regs
                float w = (u - mu) * rs * gv[n] + btv[n];
                *(short*)(lds + hbase + tswz(row, n * 2 + (lrow >> 3)) + cl) = f2bf(w);
            }
        }
        asm volatile("s_waitcnt lgkmcnt(0)" ::: "memory");

        // ---- read w in A-layout, residual from registers, coalesced NT store ----
        {
            int row = tile * 16 + lrow;
            if (row < E) {
                float* orow = out + (size_t)row * H_EDGE;
                #pragma unroll
                for (int t = 0; t < 4; ++t) {
                    bf16x8 wf = *(const bf16x8*)(lds + hbase + tswz(lrow, t * 4 + lk8));
                    bf16x8 ef = A1[t + 4];
                    f32x4 lo, hi;
                    lo[0] = bf2f(wf[0]) + bf2f(ef[0]);
                    lo[1] = bf2f(wf[1]) + bf2f(ef[1]);
                    lo[2] = bf2f(wf[2]) + bf2f(ef[2]);
                    lo[3] = bf2f(wf[3]) + bf2f(ef[3]);
                    hi[0] = bf2f(wf[4]) + bf2f(ef[4]);
                    hi[1] = bf2f(wf[5]) + bf2f(ef[5]);
                    hi[2] = bf2f(wf[6]) + bf2f(ef[6]);
                    hi[3] = bf2f(wf[7]) + bf2f(ef[7]);
                    float* dst = orow + t * 32 + lk8 * 8;
                    __builtin_nontemporal_store(lo, (f32x4*)dst);
                    __builtin_nontemporal_store(hi, (f32x4*)(dst + 4));
                }
            }
        }

        // ---- rotate pipeline state ----
        A1[4] = A1n4; A1[5] = A1n5; A1[6] = A1n6; A1[7] = A1n7;
        tile  = next;   next  = t2;
        nrowg = t2rowg; nsidx = t2s; ndidx = t2d;
    }
}

extern "C" void kernel_launch(void* const* d_in, const int* in_sizes, int n_in,
                              void* d_out, int out_size, void* d_ws, size_t ws_size,
                              hipStream_t stream) {
    const float* node  = (const float*)d_in[0];
    const float* edgef = (const float*)d_in[1];
    const int*   ei    = (const int*)d_in[2];    // int32 on device
    const float* W1    = (const float*)d_in[3];
    const float* b1    = (const float*)d_in[4];
    const float* W2    = (const float*)d_in[5];
    const float* b2    = (const float*)d_in[6];
    const float* gamma = (const float*)d_in[7];
    const float* beta  = (const float*)d_in[8];
    float* outp = (float*)d_out;
    const int E = in_sizes[2] / 2;   // edge_index is [2, E]

    hipLaunchKernelGGL(edge_update, dim3(GRID), dim3(BLOCK), 0, stream,
                       node, edgef, ei, W1, b1, W2, b2, gamma, beta, outp, E);
}

// Round 2
// 373.099 us; speedup vs baseline: 1.2098x; 1.2098x over previous
//
#include <hip/hip_runtime.h>
#include <hip/hip_bf16.h>

typedef short bf16x8 __attribute__((ext_vector_type(8)));
typedef float f32x4  __attribute__((ext_vector_type(4)));

#define H_NODE 64
#define H_EDGE 128
#define IN_DIM 256
#define WAVES  16
#define BLOCK  1024
#define GRID   256
#define LN_EPS 1e-5f

// Static LDS layout (byte offsets), 160 KiB total (full CU LDS, 1 block/CU):
//   [0,      65536): W1^T bf16: addr = col*512 + ((k*2) ^ ((col&7)<<4)),  col in [0,128), k in [0,256)
//   [65536,  98304): W2^T bf16: addr = 65536 + col*256 + ((k*2) ^ ((col&7)<<4)), k in [0,128)
//   [98304, 163840): per-wave transpose tile (16 rows x 128 bf16, 4KB x 16 waves)
//
// Register budget note (round-1 lesson): BLOCK=1024 + 160KiB LDS forces 1 block/CU,
// 4 waves/SIMD -> 128 unified VGPR+AGPR per wave, hard cap. acc is SHARED between
// GEMM1 and GEMM2 (saves 32 AGPR) to pay for the 32-reg node-gather prefetch.
// Peak live ~120. Tripwire for spills: WRITE_SIZE > 600 MB.
//
// Pipeline:
//   loop top:   cvt Fn->A1[0..3] (data arrived during prev LN/store); issue edge loads
//   GEMM1 A:    node-half MFMAs (t=0..3) cover edge-load latency
//   cvt Fe->A1[4..7]; GEMM1 B (t=4..7)
//   h-phase -> LDS -> GEMM2 (same acc, re-zeroed)
//   post-GEMM2: issue NEXT tile node gathers (Fn) + tile+2 indices
//   LN (u recomputed, not held) -> LDS -> residual store

static __device__ __forceinline__ short f2bf(float x) {
    __hip_bfloat16 h = __float2bfloat16(x);   // RNE
    return *reinterpret_cast<short*>(&h);
}

static __device__ __forceinline__ float bf2f(short s) {
    union { unsigned int u; float f; } v;
    v.u = ((unsigned int)(unsigned short)s) << 16;
    return v.f;
}

static __device__ __forceinline__ int tswz(int r, int g) {
    return r * 256 + ((g ^ ((r >> 2) << 1)) << 4);
}

static __device__ __forceinline__ bf16x8 cvt8(f32x4 lo, f32x4 hi) {
    bf16x8 f;
    f[0] = f2bf(lo[0]); f[1] = f2bf(lo[1]); f[2] = f2bf(lo[2]); f[3] = f2bf(lo[3]);
    f[4] = f2bf(hi[0]); f[5] = f2bf(hi[1]); f[6] = f2bf(hi[2]); f[7] = f2bf(hi[3]);
    return f;
}

extern "C" __global__ void __launch_bounds__(BLOCK, 4)
edge_update(const float* __restrict__ node,
            const float* __restrict__ edgef,
            const int* __restrict__ ei,          // int32 on device
            const float* __restrict__ W1, const float* __restrict__ b1,
            const float* __restrict__ W2, const float* __restrict__ b2,
            const float* __restrict__ gamma, const float* __restrict__ beta,
            float* __restrict__ out, int E)
{
    __shared__ char lds[163840];
    const int tid = threadIdx.x;

    // ---- stage W1^T (bf16, swizzled) ----
    #pragma unroll 4
    for (int i = 0; i < 32; ++i) {
        int e = tid + i * 1024;             // e < 32768; W1 is [k][n], k<256, n<128
        int k = e >> 7, n = e & 127;
        float v = W1[e];
        int addr = n * 512 + ((k * 2) ^ ((n & 7) << 4));
        *(short*)(lds + addr) = f2bf(v);
    }
    // ---- stage W2^T ----
    #pragma unroll 4
    for (int i = 0; i < 16; ++i) {
        int e = tid + i * 1024;             // e < 16384; W2 is [k][n], k<128, n<128
        int k = e >> 7, n = e & 127;
        float v = W2[e];
        int addr = 65536 + n * 256 + ((k * 2) ^ ((n & 7) << 4));
        *(short*)(lds + addr) = f2bf(v);
    }
    __syncthreads();

    const int wid   = tid >> 6;
    const int lane  = tid & 63;
    const int lrow  = lane & 15;   // A-frag row / C col / B col
    const int lk8   = lane >> 4;   // k-subchunk 0..3
    const int hbase = 98304 + wid * 4096;

    // per-lane column constants (persistent, as in the 313us baseline)
    float bias1[8], bias2[8], g8[8], bt8[8];
    #pragma unroll
    for (int n = 0; n < 8; ++n) {
        int c = n * 16 + lrow;
        bias1[n] = b1[c]; bias2[n] = b2[c]; g8[n] = gamma[c]; bt8[n] = beta[c];
    }

    const int ntiles  = (E + 15) >> 4;
    const int wstride = GRID * WAVES;

    int tile = blockIdx.x * WAVES + wid;
    if (tile >= ntiles) return;

    // ---- prologue: indices + node prefetch for tile t, indices for t+1 ----
    int rowg = tile * 16 + lrow; if (rowg >= E) rowg = E - 1;
    int sidx = ei[rowg];
    int didx = ei[E + rowg];

    f32x4 Fn0, Fn1, Fn2, Fn3, Fn4, Fn5, Fn6, Fn7;
    {
        const float* sp = node + (size_t)sidx * H_NODE + lk8 * 8;
        const float* dp = node + (size_t)didx * H_NODE + lk8 * 8;
        Fn0 = *(const f32x4*)(sp);      Fn1 = *(const f32x4*)(sp + 4);
        Fn2 = *(const f32x4*)(sp + 32); Fn3 = *(const f32x4*)(sp + 36);
        Fn4 = *(const f32x4*)(dp);      Fn5 = *(const f32x4*)(dp + 4);
        Fn6 = *(const f32x4*)(dp + 32); Fn7 = *(const f32x4*)(dp + 36);
    }
    int next  = tile + wstride;
    int nrowg = next * 16 + lrow; if (nrowg >= E) nrowg = E - 1;
    int nsidx = ei[nrowg];
    int ndidx = ei[E + nrowg];

    while (tile < ntiles) {
        // ---- fold node prefetch (arrived during previous LN/store) ----
        bf16x8 A1[8];
        A1[0] = cvt8(Fn0, Fn1);
        A1[1] = cvt8(Fn2, Fn3);
        A1[2] = cvt8(Fn4, Fn5);
        A1[3] = cvt8(Fn6, Fn7);

        // ---- issue CURRENT tile's edge loads (latency covered by GEMM1-A) ----
        const float* egp = edgef + (size_t)rowg * H_EDGE + lk8 * 8;
        f32x4 Fe0 = *(const f32x4*)(egp);
        f32x4 Fe1 = *(const f32x4*)(egp + 4);
        f32x4 Fe2 = *(const f32x4*)(egp + 32);
        f32x4 Fe3 = *(const f32x4*)(egp + 36);
        f32x4 Fe4 = *(const f32x4*)(egp + 64);
        f32x4 Fe5 = *(const f32x4*)(egp + 68);
        f32x4 Fe6 = *(const f32x4*)(egp + 96);
        f32x4 Fe7 = *(const f32x4*)(egp + 100);

        // ---- GEMM1 part A: node half (t=0..3), K accumulation order unchanged ----
        f32x4 acc[8];
        #pragma unroll
        for (int n = 0; n < 8; ++n) acc[n] = (f32x4){0.f, 0.f, 0.f, 0.f};
        #pragma unroll
        for (int n = 0; n < 8; ++n) {
            const int col = n * 16 + lrow;
            const int cb  = col * 512;
            const int sw  = (col & 7) << 4;
            #pragma unroll
            for (int t = 0; t < 4; ++t) {
                int kb = t * 64 + lk8 * 16;
                bf16x8 bfrag = *(const bf16x8*)(lds + cb + (kb ^ sw));
                acc[n] = __builtin_amdgcn_mfma_f32_16x16x32_bf16(A1[t], bfrag, acc[n], 0, 0, 0);
            }
        }

        // ---- fold edge loads, then GEMM1 part B (t=4..7) ----
        A1[4] = cvt8(Fe0, Fe1);
        A1[5] = cvt8(Fe2, Fe3);
        A1[6] = cvt8(Fe4, Fe5);
        A1[7] = cvt8(Fe6, Fe7);
        #pragma unroll
        for (int n = 0; n < 8; ++n) {
            const int col = n * 16 + lrow;
            const int cb  = col * 512;
            const int sw  = (col & 7) << 4;
            #pragma unroll
            for (int t = 4; t < 8; ++t) {
                int kb = t * 64 + lk8 * 16;
                bf16x8 bfrag = *(const bf16x8*)(lds + cb + (kb ^ sw));
                acc[n] = __builtin_amdgcn_mfma_f32_16x16x32_bf16(A1[t], bfrag, acc[n], 0, 0, 0);
            }
        }

        // ---- bias + relu -> h (bf16) to per-wave LDS (conflict-free swizzle) ----
        #pragma unroll
        for (int n = 0; n < 8; ++n) {
            const int g = n * 2 + (lrow >> 3);
            const int cl = (lrow & 7) * 2;
            #pragma unroll
            for (int i = 0; i < 4; ++i) {
                float u = fmaxf(acc[n][i] + bias1[n], 0.f);
                int row = lk8 * 4 + i;
                *(short*)(lds + hbase + tswz(row, g) + cl) = f2bf(u);
            }
        }
        // same-wave cross-lane LDS visibility: drain ds_writes before reads
        asm volatile("s_waitcnt lgkmcnt(0)" ::: "memory");

        // ---- GEMM2: [16x128] @ [128x128], REUSING acc (saves 32 AGPR) ----
        bf16x8 A2[4];
        #pragma unroll
        for (int t = 0; t < 4; ++t)
            A2[t] = *(const bf16x8*)(lds + hbase + tswz(lrow, t * 4 + lk8));

        #pragma unroll
        for (int n = 0; n < 8; ++n) acc[n] = (f32x4){0.f, 0.f, 0.f, 0.f};
        #pragma unroll
        for (int n = 0; n < 8; ++n) {
            const int col = n * 16 + lrow;
            const int cb  = 65536 + col * 256;
            const int sw  = (col & 7) << 4;
            #pragma unroll
            for (int t = 0; t < 4; ++t) {
                int kb = t * 64 + lk8 * 16;
                bf16x8 bfrag = *(const bf16x8*)(lds + cb + (kb ^ sw));
                acc[n] = __builtin_amdgcn_mfma_f32_16x16x32_bf16(A2[t], bfrag, acc[n], 0, 0, 0);
            }
        }

        // ---- issue NEXT tile's node gathers + tile+2 indices ----
        // (latency hidden under LN shfl-chain + w-write + store)
        {
            const float* sp = node + (size_t)nsidx * H_NODE + lk8 * 8;
            const float* dp = node + (size_t)ndidx * H_NODE + lk8 * 8;
            Fn0 = *(const f32x4*)(sp);      Fn1 = *(const f32x4*)(sp + 4);
            Fn2 = *(const f32x4*)(sp + 32); Fn3 = *(const f32x4*)(sp + 36);
            Fn4 = *(const f32x4*)(dp);      Fn5 = *(const f32x4*)(dp + 4);
            Fn6 = *(const f32x4*)(dp + 32); Fn7 = *(const f32x4*)(dp + 36);
        }
        int t2 = next + wstride;
        int t2rowg = t2 * 16 + lrow; if (t2rowg >= E) t2rowg = E - 1;
        int t2s = ei[t2rowg];
        int t2d = ei[E + t2rowg];

        // ---- bias2 + LayerNorm (C-layout) -> w (bf16) back through LDS ----
        #pragma unroll
        for (int i = 0; i < 4; ++i) {
            float s = 0.f, sq = 0.f;
            #pragma unroll
            for (int n = 0; n < 8; ++n) {
                float u = acc[n][i] + bias2[n];
                s  += u;
                sq += u * u;
            }
            #pragma unroll
            for (int m = 1; m < 16; m <<= 1) {
                s  += __shfl_xor(s,  m, 64);
                sq += __shfl_xor(sq, m, 64);
            }
            float mu  = s * (1.f / 128.f);
            float var = sq * (1.f / 128.f) - mu * mu;
            float rs  = rsqrtf(var + LN_EPS);
            int row = lk8 * 4 + i;
            const int cl = (lrow & 7) * 2;
            #pragma unroll
            for (int n = 0; n < 8; ++n) {
                float u = acc[n][i] + bias2[n];   // recompute: saves 8 live regs
                float w = (u - mu) * rs * g8[n] + bt8[n];
                *(short*)(lds + hbase + tswz(row, n * 2 + (lrow >> 3)) + cl) = f2bf(w);
            }
        }
        asm volatile("s_waitcnt lgkmcnt(0)" ::: "memory");

        // ---- read w in A-layout, residual from registers, coalesced store ----
        {
            int row = tile * 16 + lrow;
            if (row < E) {
                float* orow = out + (size_t)row * H_EDGE;
                #pragma unroll
                for (int t = 0; t < 4; ++t) {
                    bf16x8 wf = *(const bf16x8*)(lds + hbase + tswz(lrow, t * 4 + lk8));
                    bf16x8 ef = A1[t + 4];
                    float4 lo, hi;
                    lo.x = bf2f(wf[0]) + bf2f(ef[0]);
                    lo.y = bf2f(wf[1]) + bf2f(ef[1]);
                    lo.z = bf2f(wf[2]) + bf2f(ef[2]);
                    lo.w = bf2f(wf[3]) + bf2f(ef[3]);
                    hi.x = bf2f(wf[4]) + bf2f(ef[4]);
                    hi.y = bf2f(wf[5]) + bf2f(ef[5]);
                    hi.z = bf2f(wf[6]) + bf2f(ef[6]);
                    hi.w = bf2f(wf[7]) + bf2f(ef[7]);
                    float* dst = orow + t * 32 + lk8 * 8;
                    *(float4*)dst       = lo;
                    *(float4*)(dst + 4) = hi;
                }
            }
        }

        // ---- rotate pipeline state ----
        tile = next;  next = t2;
        rowg = nrowg; nrowg = t2rowg;
        nsidx = t2s;  ndidx = t2d;
    }
}

extern "C" void kernel_launch(void* const* d_in, const int* in_sizes, int n_in,
                              void* d_out, int out_size, void* d_ws, size_t ws_size,
                              hipStream_t stream) {
    const float* node  = (const float*)d_in[0];
    const float* edgef = (const float*)d_in[1];
    const int*   ei    = (const int*)d_in[2];    // int32 on device
    const float* W1    = (const float*)d_in[3];
    const float* b1    = (const float*)d_in[4];
    const float* W2    = (const float*)d_in[5];
    const float* b2    = (const float*)d_in[6];
    const float* gamma = (const float*)d_in[7];
    const float* beta  = (const float*)d_in[8];
    float* outp = (float*)d_out;
    const int E = in_sizes[2] / 2;   // edge_index is [2, E]

    hipLaunchKernelGGL(edge_update, dim3(GRID), dim3(BLOCK), 0, stream,
                       node, edgef, ei, W1, b1, W2, b2, gamma, beta, outp, E);
}

// Round 3
// 262.541 us; speedup vs baseline: 1.7193x; 1.4211x over previous
//
#include <hip/hip_runtime.h>
#include <hip/hip_bf16.h>

typedef short bf16x8 __attribute__((ext_vector_type(8)));
typedef float f32x4  __attribute__((ext_vector_type(4)));

#define H_NODE 64
#define H_EDGE 128
#define IN_DIM 256
#define WAVES  8
#define BLOCK  512
#define GRID   256
#define LN_EPS 1e-5f

// Static LDS layout (byte offsets), 128 KiB (1 block/CU):
//   [0,      65536): W1^T bf16: addr = col*512 + ((k*2) ^ ((col&7)<<4)),  col in [0,128), k in [0,256)
//   [65536,  98304): W2^T bf16: addr = 65536 + col*256 + ((k*2) ^ ((col&7)<<4)), k in [0,128)
//   [98304, 131072): per-wave transpose tile (16 rows x 128 bf16, 4KB x 8 waves)
//
// Round-3 structural change (Little's law): 8 waves x 256 VGPR instead of
// 16 waves x 128 VGPR. The freed registers hold the ENTIRE next tile's
// gather (24 x f32x4 = 96 VGPR: node src/dst + edge row), issued at the TOP
// of each tile and consumed at the top of the next -> loads stay in flight
// for ~the whole tile instead of a short burst. Avg bytes-in-flight per CU
// rises ~10x; HBM stops being latency-bound. Phase code (GEMM1/h/GEMM2/LN/
// store) is verbatim from the 313us champion.
// Spill tripwire: WRITE_SIZE > 600 MB.

static __device__ __forceinline__ short f2bf(float x) {
    __hip_bfloat16 h = __float2bfloat16(x);   // RNE
    return *reinterpret_cast<short*>(&h);
}

static __device__ __forceinline__ float bf2f(short s) {
    union { unsigned int u; float f; } v;
    v.u = ((unsigned int)(unsigned short)s) << 16;
    return v.f;
}

static __device__ __forceinline__ int tswz(int r, int g) {
    return r * 256 + ((g ^ ((r >> 2) << 1)) << 4);
}

static __device__ __forceinline__ bf16x8 cvt8(f32x4 lo, f32x4 hi) {
    bf16x8 f;
    f[0] = f2bf(lo[0]); f[1] = f2bf(lo[1]); f[2] = f2bf(lo[2]); f[3] = f2bf(lo[3]);
    f[4] = f2bf(hi[0]); f[5] = f2bf(hi[1]); f[6] = f2bf(hi[2]); f[7] = f2bf(hi[3]);
    return f;
}

extern "C" __global__ void __launch_bounds__(BLOCK, 2)
edge_update(const float* __restrict__ node,
            const float* __restrict__ edgef,
            const int* __restrict__ ei,          // int32 on device
            const float* __restrict__ W1, const float* __restrict__ b1,
            const float* __restrict__ W2, const float* __restrict__ b2,
            const float* __restrict__ gamma, const float* __restrict__ beta,
            float* __restrict__ out, int E)
{
    __shared__ char lds[131072];
    const int tid = threadIdx.x;

    // ---- stage W1^T (bf16, swizzled) ----
    #pragma unroll 4
    for (int i = 0; i < 64; ++i) {
        int e = tid + i * BLOCK;            // e < 32768; W1 is [k][n], k<256, n<128
        int k = e >> 7, n = e & 127;
        float v = W1[e];
        int addr = n * 512 + ((k * 2) ^ ((n & 7) << 4));
        *(short*)(lds + addr) = f2bf(v);
    }
    // ---- stage W2^T ----
    #pragma unroll 4
    for (int i = 0; i < 32; ++i) {
        int e = tid + i * BLOCK;            // e < 16384; W2 is [k][n], k<128, n<128
        int k = e >> 7, n = e & 127;
        float v = W2[e];
        int addr = 65536 + n * 256 + ((k * 2) ^ ((n & 7) << 4));
        *(short*)(lds + addr) = f2bf(v);
    }
    __syncthreads();

    const int wid   = tid >> 6;
    const int lane  = tid & 63;
    const int lrow  = lane & 15;   // A-frag row / C col / B col
    const int lk8   = lane >> 4;   // k-subchunk 0..3
    const int hbase = 98304 + wid * 4096;

    // per-lane column constants (persistent; plenty of regs at 2 waves/SIMD)
    float bias1[8], bias2[8], g8[8], bt8[8];
    #pragma unroll
    for (int n = 0; n < 8; ++n) {
        int c = n * 16 + lrow;
        bias1[n] = b1[c]; bias2[n] = b2[c]; g8[n] = gamma[c]; bt8[n] = beta[c];
    }

    const int ntiles  = (E + 15) >> 4;
    const int wstride = GRID * WAVES;

    int tile = blockIdx.x * WAVES + wid;
    if (tile >= ntiles) return;

    // ---- prologue: indices + staged gather for tile t; indices for t+1 ----
    int rowg = tile * 16 + lrow; if (rowg >= E) rowg = E - 1;
    int sidx = ei[rowg];
    int didx = ei[E + rowg];

    f32x4 Sn0, Sn1, Sn2, Sn3, Sn4, Sn5, Sn6, Sn7;   // node src/dst raw
    f32x4 Se0, Se1, Se2, Se3, Se4, Se5, Se6, Se7;   // edge row raw
    {
        const float* sp = node + (size_t)sidx * H_NODE + lk8 * 8;
        const float* dp = node + (size_t)didx * H_NODE + lk8 * 8;
        const float* ep = edgef + (size_t)rowg * H_EDGE + lk8 * 8;
        Sn0 = *(const f32x4*)(sp);      Sn1 = *(const f32x4*)(sp + 4);
        Sn2 = *(const f32x4*)(sp + 32); Sn3 = *(const f32x4*)(sp + 36);
        Sn4 = *(const f32x4*)(dp);      Sn5 = *(const f32x4*)(dp + 4);
        Sn6 = *(const f32x4*)(dp + 32); Sn7 = *(const f32x4*)(dp + 36);
        Se0 = *(const f32x4*)(ep);      Se1 = *(const f32x4*)(ep + 4);
        Se2 = *(const f32x4*)(ep + 32); Se3 = *(const f32x4*)(ep + 36);
        Se4 = *(const f32x4*)(ep + 64); Se5 = *(const f32x4*)(ep + 68);
        Se6 = *(const f32x4*)(ep + 96); Se7 = *(const f32x4*)(ep + 100);
    }
    int next  = tile + wstride;
    int nrowg = next * 16 + lrow; if (nrowg >= E) nrowg = E - 1;
    int nsidx = ei[nrowg];
    int ndidx = ei[E + nrowg];

    while (tile < ntiles) {
        // ---- fold staged gather (issued one full tile ago) into A1 ----
        bf16x8 A1[8];
        A1[0] = cvt8(Sn0, Sn1);
        A1[1] = cvt8(Sn2, Sn3);
        A1[2] = cvt8(Sn4, Sn5);
        A1[3] = cvt8(Sn6, Sn7);
        A1[4] = cvt8(Se0, Se1);
        A1[5] = cvt8(Se2, Se3);
        A1[6] = cvt8(Se4, Se5);
        A1[7] = cvt8(Se6, Se7);

        // ---- issue NEXT tile's FULL gather burst (in flight all tile) ----
        {
            const float* sp = node + (size_t)nsidx * H_NODE + lk8 * 8;
            const float* dp = node + (size_t)ndidx * H_NODE + lk8 * 8;
            const float* ep = edgef + (size_t)nrowg * H_EDGE + lk8 * 8;
            Sn0 = *(const f32x4*)(sp);      Sn1 = *(const f32x4*)(sp + 4);
            Sn2 = *(const f32x4*)(sp + 32); Sn3 = *(const f32x4*)(sp + 36);
            Sn4 = *(const f32x4*)(dp);      Sn5 = *(const f32x4*)(dp + 4);
            Sn6 = *(const f32x4*)(dp + 32); Sn7 = *(const f32x4*)(dp + 36);
            Se0 = *(const f32x4*)(ep);      Se1 = *(const f32x4*)(ep + 4);
            Se2 = *(const f32x4*)(ep + 32); Se3 = *(const f32x4*)(ep + 36);
            Se4 = *(const f32x4*)(ep + 64); Se5 = *(const f32x4*)(ep + 68);
            Se6 = *(const f32x4*)(ep + 96); Se7 = *(const f32x4*)(ep + 100);
        }
        // ---- prefetch tile+2 indices ----
        int t2 = next + wstride;
        int t2rowg = t2 * 16 + lrow; if (t2rowg >= E) t2rowg = E - 1;
        int t2s = ei[t2rowg];
        int t2d = ei[E + t2rowg];

        // ---- GEMM1: [16x256] @ [256x128] ----
        f32x4 acc[8];
        #pragma unroll
        for (int n = 0; n < 8; ++n) acc[n] = (f32x4){0.f, 0.f, 0.f, 0.f};
        #pragma unroll
        for (int n = 0; n < 8; ++n) {
            const int col = n * 16 + lrow;
            const int cb  = col * 512;
            const int sw  = (col & 7) << 4;
            #pragma unroll
            for (int t = 0; t < 8; ++t) {
                int kb = t * 64 + lk8 * 16;
                bf16x8 bfrag = *(const bf16x8*)(lds + cb + (kb ^ sw));
                acc[n] = __builtin_amdgcn_mfma_f32_16x16x32_bf16(A1[t], bfrag, acc[n], 0, 0, 0);
            }
        }

        // ---- bias + relu -> h (bf16) to per-wave LDS (conflict-free swizzle) ----
        #pragma unroll
        for (int n = 0; n < 8; ++n) {
            const int g = n * 2 + (lrow >> 3);
            const int cl = (lrow & 7) * 2;
            #pragma unroll
            for (int i = 0; i < 4; ++i) {
                float u = fmaxf(acc[n][i] + bias1[n], 0.f);
                int row = lk8 * 4 + i;
                *(short*)(lds + hbase + tswz(row, g) + cl) = f2bf(u);
            }
        }
        // same-wave cross-lane LDS visibility: drain ds_writes before reads
        asm volatile("s_waitcnt lgkmcnt(0)" ::: "memory");

        // ---- GEMM2: [16x128] @ [128x128] ----
        bf16x8 A2[4];
        #pragma unroll
        for (int t = 0; t < 4; ++t)
            A2[t] = *(const bf16x8*)(lds + hbase + tswz(lrow, t * 4 + lk8));

        f32x4 acc2[8];
        #pragma unroll
        for (int n = 0; n < 8; ++n) acc2[n] = (f32x4){0.f, 0.f, 0.f, 0.f};
        #pragma unroll
        for (int n = 0; n < 8; ++n) {
            const int col = n * 16 + lrow;
            const int cb  = 65536 + col * 256;
            const int sw  = (col & 7) << 4;
            #pragma unroll
            for (int t = 0; t < 4; ++t) {
                int kb = t * 64 + lk8 * 16;
                bf16x8 bfrag = *(const bf16x8*)(lds + cb + (kb ^ sw));
                acc2[n] = __builtin_amdgcn_mfma_f32_16x16x32_bf16(A2[t], bfrag, acc2[n], 0, 0, 0);
            }
        }

        // ---- bias2 + LayerNorm (C-layout) -> w (bf16) back through LDS ----
        #pragma unroll
        for (int i = 0; i < 4; ++i) {
            float u[8];
            float s = 0.f, sq = 0.f;
            #pragma unroll
            for (int n = 0; n < 8; ++n) {
                u[n] = acc2[n][i] + bias2[n];
                s  += u[n];
                sq += u[n] * u[n];
            }
            #pragma unroll
            for (int m = 1; m < 16; m <<= 1) {
                s  += __shfl_xor(s,  m, 64);
                sq += __shfl_xor(sq, m, 64);
            }
            float mu  = s * (1.f / 128.f);
            float var = sq * (1.f / 128.f) - mu * mu;
            float rs  = rsqrtf(var + LN_EPS);
            int row = lk8 * 4 + i;
            const int cl = (lrow & 7) * 2;
            #pragma unroll
            for (int n = 0; n < 8; ++n) {
                float w = (u[n] - mu) * rs * g8[n] + bt8[n];
                *(short*)(lds + hbase + tswz(row, n * 2 + (lrow >> 3)) + cl) = f2bf(w);
            }
        }
        asm volatile("s_waitcnt lgkmcnt(0)" ::: "memory");

        // ---- read w in A-layout, residual from registers, coalesced store ----
        {
            int row = tile * 16 + lrow;
            if (row < E) {
                float* orow = out + (size_t)row * H_EDGE;
                #pragma unroll
                for (int t = 0; t < 4; ++t) {
                    bf16x8 wf = *(const bf16x8*)(lds + hbase + tswz(lrow, t * 4 + lk8));
                    bf16x8 ef = A1[t + 4];
                    float4 lo, hi;
                    lo.x = bf2f(wf[0]) + bf2f(ef[0]);
                    lo.y = bf2f(wf[1]) + bf2f(ef[1]);
                    lo.z = bf2f(wf[2]) + bf2f(ef[2]);
                    lo.w = bf2f(wf[3]) + bf2f(ef[3]);
                    hi.x = bf2f(wf[4]) + bf2f(ef[4]);
                    hi.y = bf2f(wf[5]) + bf2f(ef[5]);
                    hi.z = bf2f(wf[6]) + bf2f(ef[6]);
                    hi.w = bf2f(wf[7]) + bf2f(ef[7]);
                    float* dst = orow + t * 32 + lk8 * 8;
                    *(float4*)dst       = lo;
                    *(float4*)(dst + 4) = hi;
                }
            }
        }

        // ---- rotate pipeline state ----
        tile = next;  next = t2;
        nrowg = t2rowg; nsidx = t2s; ndidx = t2d;
    }
}

extern "C" void kernel_launch(void* const* d_in, const int* in_sizes, int n_in,
                              void* d_out, int out_size, void* d_ws, size_t ws_size,
                              hipStream_t stream) {
    const float* node  = (const float*)d_in[0];
    const float* edgef = (const float*)d_in[1];
    const int*   ei    = (const int*)d_in[2];    // int32 on device
    const float* W1    = (const float*)d_in[3];
    const float* b1    = (const float*)d_in[4];
    const float* W2    = (const float*)d_in[5];
    const float* b2    = (const float*)d_in[6];
    const float* gamma = (const float*)d_in[7];
    const float* beta  = (const float*)d_in[8];
    float* outp = (float*)d_out;
    const int E = in_sizes[2] / 2;   // edge_index is [2, E]

    hipLaunchKernelGGL(edge_update, dim3(GRID), dim3(BLOCK), 0, stream,
                       node, edgef, ei, W1, b1, W2, b2, gamma, beta, outp, E);
}